// Round 6
// baseline (69.567 us; speedup 1.0000x reference)
//
#include <hip/hip_runtime.h>
#include <hip/hip_bf16.h>

typedef __attribute__((ext_vector_type(8))) short short8;
typedef __attribute__((ext_vector_type(8))) unsigned short u16x8;
typedef __attribute__((ext_vector_type(4))) unsigned short u16x4;
typedef __attribute__((ext_vector_type(4))) float f32x4;

constexpr int NB = 64;     // batch
constexpr int NL = 96;     // time / conv channels
constexpr int NC = 2048;   // feature / conv spatial
constexpr int TT = 64;     // conv spatial tile per block
constexpr int KTOT = 288;  // conv GEMM K = 96 ch * 3 taps, k = tau*96 + i
constexpr int LROW = 104;  // conv LDS row pitch (bf16)
constexpr int CW = 32;     // decomp c-chunk width
constexpr int MPITCH = 100;// decomp mm/res LDS row pitch (u16): 200B%8==0, 4-way max
constexpr float LOG2E = 1.44269504088896340736f;

__device__ inline unsigned short f2bf(float f) {
    union { float f; unsigned u; } v; v.f = f;
    unsigned r = v.u + 0x7fff + ((v.u >> 16) & 1);   // RNE
    return (unsigned short)(r >> 16);
}
__device__ inline unsigned cvt_pk_bf16(float lo, float hi) {
    unsigned r;
    asm("v_cvt_pk_bf16_f32 %0, %1, %2" : "=v"(r) : "v"(lo), "v"(hi));
    return r;
}
__device__ inline float fexp2(float x) {
    float r; asm("v_exp_f32 %0, %1" : "=v"(r) : "v"(x)); return r;
}
__device__ inline float frcp(float x) {
    float r; asm("v_rcp_f32 %0, %1" : "=v"(r) : "v"(x)); return r;
}

// ---------------------------------------------------------------------------
// Weight permute+convert: Aw[o][k], k = tau*96 + i, bf16.
// ---------------------------------------------------------------------------
__global__ void prep_aw(const float* __restrict__ w, unsigned short* __restrict__ aw)
{
    int idx = blockIdx.x * 256 + threadIdx.x;
    if (idx >= NL * KTOT) return;
    int o = idx / KTOT, k = idx - o * KTOT;
    int tau = k / NL, i = k - tau * NL;
    aw[idx] = f2bf(w[(o * NL + i) * 3 + tau]);
}

// ---------------------------------------------------------------------------
// Decomp v2. Block = (b, 32-wide c chunk), 256 threads, ~28 KB LDS ->
// 4 blocks/CU = 32 waves/CU.
//  A: stage x into LDS [120][32] f32 with replicate pad rows (l = -12..107)
//     -- makes every window sum exact with NO edge cases.
//  B: thread = (c, 12-l strip): sliding windows s5/s13/s25 (2 LDS reads +
//     2 adds per window per step), softmax gate, res/mm -> bf16 LDS.
//  C: stream res/mm out as contiguous 8B/lane stores (dense, no RFO).
// ---------------------------------------------------------------------------
__global__ __launch_bounds__(256) void decomp_v2(
    const float* __restrict__ x,
    const float* __restrict__ gw,
    const float* __restrict__ gb,
    unsigned short* __restrict__ resT,   // [64][2048][96] bf16
    unsigned short* __restrict__ mmT)
{
    __shared__ float sxf[120][CW];
    __shared__ unsigned short sres[CW][MPITCH];
    __shared__ unsigned short smm[CW][MPITCH];

    int b = blockIdx.x;
    int c0 = blockIdx.y * CW;
    size_t xb = (size_t)b * NL * NC;

    // ---- Phase A: stage (coalesced; rows clamped for replicate pad) ----
    for (int u = threadIdx.x; u < 120 * CW; u += 256) {
        int rr = u >> 5, c = u & (CW - 1);
        int lsrc = rr - 12;
        lsrc = lsrc < 0 ? 0 : (lsrc > 95 ? 95 : lsrc);
        sxf[rr][c] = x[xb + (size_t)lsrc * NC + c0 + c];
    }
    __syncthreads();

    // ---- Phase B: sliding-window means + gate ----
    {
        int c = threadIdx.x & (CW - 1);
        int l0 = (threadIdx.x >> 5) * 12;   // 8 strips of 12

        float w0 = gw[0] * LOG2E, w1 = gw[1] * LOG2E, w2 = gw[2] * LOG2E;
        float b0 = gb[0] * LOG2E, b1 = gb[1] * LOG2E, b2 = gb[2] * LOG2E;

        // init sums for l = l0 (LDS row of series index l is l+12)
        float s5 = 0.0f, s13 = 0.0f, s25 = 0.0f;
#pragma unroll
        for (int d = 10; d <= 14; ++d) s5 += sxf[l0 + d][c];
        s13 = s5;
#pragma unroll
        for (int d = 6; d <= 9; ++d)  s13 += sxf[l0 + d][c];
#pragma unroll
        for (int d = 15; d <= 18; ++d) s13 += sxf[l0 + d][c];
        s25 = s13;
#pragma unroll
        for (int d = 0; d <= 5; ++d)  s25 += sxf[l0 + d][c];
#pragma unroll
        for (int d = 19; d <= 24; ++d) s25 += sxf[l0 + d][c];

        float pr = 0.0f, pm = 0.0f;
#pragma unroll
        for (int j = 0; j < 12; ++j) {
            const int l = l0 + j;
            if (j > 0) {
                s25 += sxf[l + 24][c] - sxf[l - 1][c];
                s13 += sxf[l + 18][c] - sxf[l + 5][c];
                s5  += sxf[l + 14][c] - sxf[l + 9][c];
            }
            float xl = sxf[l + 12][c];
            float e0 = fexp2(fmaf(xl, w0, b0));
            float e1 = fexp2(fmaf(xl, w1, b1));
            float e2 = fexp2(fmaf(xl, w2, b2));
            float inv = frcp(e0 + e1 + e2);
            float mmv = fmaf(s5 * 0.2f, e0,
                        fmaf(s13 * (1.0f / 13.0f), e1,
                             s25 * 0.04f * e2)) * inv;
            float rv = xl - mmv;
            if ((j & 1) == 0) { pr = rv; pm = mmv; }
            else {
                *(unsigned*)(&sres[c][l - 1]) = cvt_pk_bf16(pr, rv);
                *(unsigned*)(&smm[c][l - 1])  = cvt_pk_bf16(pm, mmv);
            }
        }
    }
    __syncthreads();

    // ---- Phase C: dense streaming store (8B/lane, contiguous per wave) ----
    for (int u = threadIdx.x; u < CW * 24; u += 256) {
        int c = u / 24, h = u - c * 24;
        u16x4 rv = *(const u16x4*)(&sres[c][h * 4]);
        u16x4 mv = *(const u16x4*)(&smm[c][h * 4]);
        size_t gb_ = ((size_t)b * NC + c0 + c) * NL + h * 4;
        *(u16x4*)(resT + gb_) = rv;
        *(u16x4*)(mmT + gb_)  = mv;
    }
}

// ---------------------------------------------------------------------------
// Conv: both circular convs as one bf16 MFMA GEMM (R1-proven, ~8 us).
//   out[o][t] = sum_k Aw[o][k] * B[k][t],  B[k=tau*96+i][t] = X[i][t+tau-1]
// ---------------------------------------------------------------------------
__global__ __launch_bounds__(256) void conv_mfma(
    const unsigned short* __restrict__ resT,
    const unsigned short* __restrict__ mmT,
    const unsigned short* __restrict__ aw,
    float* __restrict__ out0,
    float* __restrict__ out1)
{
    __shared__ unsigned short sx[2][TT + 2][LROW];

    int b = blockIdx.x;
    int t0 = blockIdx.y * TT;
    size_t xb = (size_t)b * NC * NL;

    for (int idx = threadIdx.x; idx < 2 * (TT + 2) * 12; idx += 256) {
        int sig = idx / ((TT + 2) * 12);
        int rem = idx - sig * (TT + 2) * 12;
        int row = rem / 12, ch = rem - row * 12;
        int t = (t0 - 1 + row) & (NC - 1);
        const unsigned short* src = sig ? mmT : resT;
        u16x8 v = *(const u16x8*)(src + xb + (size_t)t * NL + ch * 8);
        *(u16x8*)(&sx[sig][row][ch * 8]) = v;
    }

    int lane = threadIdx.x & 63;
    int wv = threadIdx.x >> 6;
    int mg = wv & 1, ng = wv >> 1;
    int lr = lane & 15, lk = lane >> 4;

    f32x4 acc[3][2][2] = {};

    const unsigned short* abase = aw + (size_t)(mg * 48 + lr) * KTOT + lk * 8;
    short8 aCur[3], aNxt[3];
#pragma unroll
    for (int mt = 0; mt < 3; ++mt)
        aCur[mt] = *(const short8*)(abase + mt * 16 * KTOT);

    __syncthreads();

#pragma unroll
    for (int ks = 0; ks < 9; ++ks) {
        if (ks < 8) {
#pragma unroll
            for (int mt = 0; mt < 3; ++mt)
                aNxt[mt] = *(const short8*)(abase + mt * 16 * KTOT + (ks + 1) * 32);
        }
        const int tau = ks / 3;
        const int i0 = (ks - tau * 3) * 32;
        short8 bf[2][2];
#pragma unroll
        for (int nt = 0; nt < 2; ++nt) {
            int r = ng * 32 + nt * 16 + lr + tau;
#pragma unroll
            for (int sig = 0; sig < 2; ++sig)
                bf[nt][sig] = *(const short8*)(&sx[sig][r][i0 + lk * 8]);
        }
#pragma unroll
        for (int mt = 0; mt < 3; ++mt)
#pragma unroll
            for (int nt = 0; nt < 2; ++nt)
#pragma unroll
                for (int sig = 0; sig < 2; ++sig)
                    acc[mt][nt][sig] = __builtin_amdgcn_mfma_f32_16x16x32_bf16(
                        aCur[mt], bf[nt][sig], acc[mt][nt][sig], 0, 0, 0);
#pragma unroll
        for (int mt = 0; mt < 3; ++mt) aCur[mt] = aNxt[mt];
    }

    size_t ob = (size_t)b * NL * NC;
    int tw = t0 + ng * 32 + lr;
#pragma unroll
    for (int mt = 0; mt < 3; ++mt) {
        int o0 = mg * 48 + mt * 16 + lk * 4;
#pragma unroll
        for (int nt = 0; nt < 2; ++nt) {
#pragma unroll
            for (int r4 = 0; r4 < 4; ++r4) {
                out0[ob + (size_t)(o0 + r4) * NC + tw + nt * 16] = acc[mt][nt][0][r4];
                out1[ob + (size_t)(o0 + r4) * NC + tw + nt * 16] = acc[mt][nt][1][r4];
            }
        }
    }
}

extern "C" void kernel_launch(void* const* d_in, const int* in_sizes, int n_in,
                              void* d_out, int out_size, void* d_ws, size_t ws_size,
                              hipStream_t stream)
{
    const float* x      = (const float*)d_in[0];
    const float* conv_w = (const float*)d_in[1];
    const float* gate_w = (const float*)d_in[2];
    const float* gate_b = (const float*)d_in[3];

    float* out0 = (float*)d_out;
    float* out1 = out0 + (size_t)NB * NL * NC;

    unsigned short* resT = (unsigned short*)d_ws;          // [64][2048][96] bf16
    unsigned short* mmT  = resT + (size_t)NB * NC * NL;
    unsigned short* awb  = mmT  + (size_t)NB * NC * NL;    // [96][288] bf16

    prep_aw<<<dim3((NL * KTOT + 255) / 256), 256, 0, stream>>>(conv_w, awb);
    decomp_v2<<<dim3(NB, NC / CW), 256, 0, stream>>>(x, gate_w, gate_b, resT, mmT);
    conv_mfma<<<dim3(NB, NC / TT), 256, 0, stream>>>(resT, mmT, awb, out0, out1);
}

// Round 7
// 66.268 us; speedup vs baseline: 1.0498x; 1.0498x over previous
//
#include <hip/hip_runtime.h>
#include <hip/hip_bf16.h>

typedef __attribute__((ext_vector_type(8))) short short8;
typedef __attribute__((ext_vector_type(8))) unsigned short u16x8;
typedef __attribute__((ext_vector_type(4))) float f32x4;

constexpr int NB = 64;     // batch
constexpr int NL = 96;     // time / conv channels
constexpr int NC = 2048;   // feature / conv spatial
constexpr int TT = 64;     // conv spatial tile per block
constexpr int KTOT = 288;  // conv GEMM K = 96 ch * 3 taps, k = tau*96 + i
constexpr int LROW = 104;  // conv LDS row pitch (bf16)
constexpr float LOG2E = 1.44269504088896340736f;

__device__ inline unsigned short f2bf(float f) {
    union { float f; unsigned u; } v; v.f = f;
    unsigned r = v.u + 0x7fff + ((v.u >> 16) & 1);   // RNE
    return (unsigned short)(r >> 16);
}
__device__ inline unsigned cvt_pk_bf16(float lo, float hi) {
    unsigned r;
    asm("v_cvt_pk_bf16_f32 %0, %1, %2" : "=v"(r) : "v"(lo), "v"(hi));
    return r;
}
__device__ inline float fexp2(float x) {
    float r; asm("v_exp_f32 %0, %1" : "=v"(r) : "v"(x)); return r;
}
__device__ inline float frcp(float x) {
    float r; asm("v_rcp_f32 %0, %1" : "=v"(r) : "v"(x)); return r;
}

// ---------------------------------------------------------------------------
// Weight permute+convert: Aw[o][k], k = tau*96 + i, bf16.
// ---------------------------------------------------------------------------
__global__ void prep_aw(const float* __restrict__ w, unsigned short* __restrict__ aw)
{
    int idx = blockIdx.x * 256 + threadIdx.x;
    if (idx >= NL * KTOT) return;
    int o = idx / KTOT, k = idx - o * KTOT;
    int tau = k / NL, i = k - tau * NL;
    aw[idx] = f2bf(w[(o * NL + i) * 3 + tau]);
}

// ---------------------------------------------------------------------------
// Decomp v3: fillBuffer-shaped. Thread = (b, c, strip of 32 l). No LDS, no
// barriers, no serial cumsum: batch-load 44-56 independent f32, sliding-
// window sums in registers (compile-time indices; clamp = replicate pad),
// softmax gate, store res/mm as one aligned 64 B run per signal per lane.
// ---------------------------------------------------------------------------
template<int Q>
__device__ __forceinline__ void decomp_strip(
    const float* __restrict__ xp,        // &x[b][0][c], row stride NC
    unsigned short* __restrict__ rp,     // &resT[(b*NC+c)*NL]
    unsigned short* __restrict__ mp,
    float w0, float w1, float w2, float b0, float b1, float b2)
{
    constexpr int L0 = 32 * Q;
    constexpr int R0 = (Q == 0) ? 0 : L0 - 12;
    constexpr int R1 = (Q == 2) ? 95 : L0 + 43;
    constexpr int NR = R1 - R0 + 1;      // 44 / 56 / 44

    // independent load batch (one vmcnt drain, no chains)
    float xv[NR];
#pragma unroll
    for (int j = 0; j < NR; ++j)
        xv[j] = xp[(size_t)(R0 + j) * NC];

    // padded-series value at row r (compile-time r, clamp = replicate pad)
#define VAL(r) xv[((r) < R0 ? R0 : ((r) > R1 ? R1 : (r))) - R0]

    float s5 = 0.0f, s13 = 0.0f, s25 = 0.0f;
#pragma unroll
    for (int d = -12; d <= 12; ++d) {
        float v = VAL(L0 + d);
        s25 += v;
        if (d >= -6 && d <= 6) s13 += v;
        if (d >= -2 && d <= 2) s5 += v;
    }

    unsigned rd[16], md[16];
    float pr = 0.0f, pm = 0.0f;
#pragma unroll
    for (int i = 0; i < 32; ++i) {
        const int l = L0 + i;
        if (i > 0) {
            s25 += VAL(l + 12) - VAL(l - 13);
            s13 += VAL(l + 6)  - VAL(l - 7);
            s5  += VAL(l + 2)  - VAL(l - 3);
        }
        float xl = VAL(l);
        float e0 = fexp2(fmaf(xl, w0, b0));
        float e1 = fexp2(fmaf(xl, w1, b1));
        float e2 = fexp2(fmaf(xl, w2, b2));
        float inv = frcp(e0 + e1 + e2);
        float mmv = fmaf(s5 * 0.2f, e0,
                    fmaf(s13 * (1.0f / 13.0f), e1,
                         s25 * 0.04f * e2)) * inv;
        float rv = xl - mmv;
        if ((i & 1) == 0) { pr = rv; pm = mmv; }
        else {
            rd[i >> 1] = cvt_pk_bf16(pr, rv);
            md[i >> 1] = cvt_pk_bf16(pm, mmv);
        }
    }
#undef VAL

#pragma unroll
    for (int v = 0; v < 4; ++v) {
        union { u16x8 vv; unsigned d[4]; } o;
        o.d[0] = rd[v*4]; o.d[1] = rd[v*4+1]; o.d[2] = rd[v*4+2]; o.d[3] = rd[v*4+3];
        *(u16x8*)(rp + L0 + v * 8) = o.vv;
        o.d[0] = md[v*4]; o.d[1] = md[v*4+1]; o.d[2] = md[v*4+2]; o.d[3] = md[v*4+3];
        *(u16x8*)(mp + L0 + v * 8) = o.vv;
    }
}

__global__ __launch_bounds__(256) void decomp_v3(
    const float* __restrict__ x,
    const float* __restrict__ gw,
    const float* __restrict__ gb,
    unsigned short* __restrict__ resT,   // [64][2048][96] bf16
    unsigned short* __restrict__ mmT)
{
    int idx = blockIdx.x * 256 + threadIdx.x;   // ((b*3 + q)*2048 + c)
    int c = idx & (NC - 1);
    int bq = idx >> 11;
    int b = bq / 3, q = bq - b * 3;             // uniform across the block

    const float* xp = x + (size_t)b * NL * NC + c;
    unsigned short* rp = resT + ((size_t)b * NC + c) * NL;
    unsigned short* mp = mmT  + ((size_t)b * NC + c) * NL;

    float w0 = gw[0] * LOG2E, w1 = gw[1] * LOG2E, w2 = gw[2] * LOG2E;
    float b0 = gb[0] * LOG2E, b1 = gb[1] * LOG2E, b2 = gb[2] * LOG2E;

    if (q == 0)      decomp_strip<0>(xp, rp, mp, w0, w1, w2, b0, b1, b2);
    else if (q == 1) decomp_strip<1>(xp, rp, mp, w0, w1, w2, b0, b1, b2);
    else             decomp_strip<2>(xp, rp, mp, w0, w1, w2, b0, b1, b2);
}

// ---------------------------------------------------------------------------
// Conv: both circular convs as one bf16 MFMA GEMM (R1-proven).
//   out[o][t] = sum_k Aw[o][k] * B[k][t],  B[k=tau*96+i][t] = X[i][t+tau-1]
// ---------------------------------------------------------------------------
__global__ __launch_bounds__(256) void conv_mfma(
    const unsigned short* __restrict__ resT,
    const unsigned short* __restrict__ mmT,
    const unsigned short* __restrict__ aw,
    float* __restrict__ out0,
    float* __restrict__ out1)
{
    __shared__ unsigned short sx[2][TT + 2][LROW];

    int b = blockIdx.x;
    int t0 = blockIdx.y * TT;
    size_t xb = (size_t)b * NC * NL;

    for (int idx = threadIdx.x; idx < 2 * (TT + 2) * 12; idx += 256) {
        int sig = idx / ((TT + 2) * 12);
        int rem = idx - sig * (TT + 2) * 12;
        int row = rem / 12, ch = rem - row * 12;
        int t = (t0 - 1 + row) & (NC - 1);
        const unsigned short* src = sig ? mmT : resT;
        u16x8 v = *(const u16x8*)(src + xb + (size_t)t * NL + ch * 8);
        *(u16x8*)(&sx[sig][row][ch * 8]) = v;
    }

    int lane = threadIdx.x & 63;
    int wv = threadIdx.x >> 6;
    int mg = wv & 1, ng = wv >> 1;
    int lr = lane & 15, lk = lane >> 4;

    f32x4 acc[3][2][2] = {};

    const unsigned short* abase = aw + (size_t)(mg * 48 + lr) * KTOT + lk * 8;
    short8 aCur[3], aNxt[3];
#pragma unroll
    for (int mt = 0; mt < 3; ++mt)
        aCur[mt] = *(const short8*)(abase + mt * 16 * KTOT);

    __syncthreads();

#pragma unroll
    for (int ks = 0; ks < 9; ++ks) {
        if (ks < 8) {
#pragma unroll
            for (int mt = 0; mt < 3; ++mt)
                aNxt[mt] = *(const short8*)(abase + mt * 16 * KTOT + (ks + 1) * 32);
        }
        const int tau = ks / 3;
        const int i0 = (ks - tau * 3) * 32;
        short8 bf[2][2];
#pragma unroll
        for (int nt = 0; nt < 2; ++nt) {
            int r = ng * 32 + nt * 16 + lr + tau;
#pragma unroll
            for (int sig = 0; sig < 2; ++sig)
                bf[nt][sig] = *(const short8*)(&sx[sig][r][i0 + lk * 8]);
        }
#pragma unroll
        for (int mt = 0; mt < 3; ++mt)
#pragma unroll
            for (int nt = 0; nt < 2; ++nt)
#pragma unroll
                for (int sig = 0; sig < 2; ++sig)
                    acc[mt][nt][sig] = __builtin_amdgcn_mfma_f32_16x16x32_bf16(
                        aCur[mt], bf[nt][sig], acc[mt][nt][sig], 0, 0, 0);
#pragma unroll
        for (int mt = 0; mt < 3; ++mt) aCur[mt] = aNxt[mt];
    }

    size_t ob = (size_t)b * NL * NC;
    int tw = t0 + ng * 32 + lr;
#pragma unroll
    for (int mt = 0; mt < 3; ++mt) {
        int o0 = mg * 48 + mt * 16 + lk * 4;
#pragma unroll
        for (int nt = 0; nt < 2; ++nt) {
#pragma unroll
            for (int r4 = 0; r4 < 4; ++r4) {
                out0[ob + (size_t)(o0 + r4) * NC + tw + nt * 16] = acc[mt][nt][0][r4];
                out1[ob + (size_t)(o0 + r4) * NC + tw + nt * 16] = acc[mt][nt][1][r4];
            }
        }
    }
}

extern "C" void kernel_launch(void* const* d_in, const int* in_sizes, int n_in,
                              void* d_out, int out_size, void* d_ws, size_t ws_size,
                              hipStream_t stream)
{
    const float* x      = (const float*)d_in[0];
    const float* conv_w = (const float*)d_in[1];
    const float* gate_w = (const float*)d_in[2];
    const float* gate_b = (const float*)d_in[3];

    float* out0 = (float*)d_out;
    float* out1 = out0 + (size_t)NB * NL * NC;

    unsigned short* resT = (unsigned short*)d_ws;          // [64][2048][96] bf16
    unsigned short* mmT  = resT + (size_t)NB * NC * NL;
    unsigned short* awb  = mmT  + (size_t)NB * NC * NL;    // [96][288] bf16

    prep_aw<<<dim3((NL * KTOT + 255) / 256), 256, 0, stream>>>(conv_w, awb);
    decomp_v3<<<dim3((NB * 3 * NC) / 256), 256, 0, stream>>>(x, gate_w, gate_b, resT, mmT);
    conv_mfma<<<dim3(NB, NC / TT), 256, 0, stream>>>(resT, mmT, awb, out0, out1);
}